// Round 1
// baseline (311.778 us; speedup 1.0000x reference)
//
#include <hip/hip_runtime.h>

#define NROW 10000
#define NF 256
#define KF 512
#define MP 10048   // 157*64, padded row/K extent
#define NTILES 157

typedef __attribute__((ext_vector_type(8))) short short8x;
typedef __attribute__((ext_vector_type(4))) float f32x4;

__device__ __forceinline__ unsigned short bf16rne(float f){
  unsigned int u = __builtin_bit_cast(unsigned int, f);
  u += 0x7fffu + ((u >> 16) & 1u);   // round-to-nearest-even
  return (unsigned short)(u >> 16);
}

// ---------------- Kernel 1: dinv[i] = rsqrt(deg_i), deg_i = sum_j Ahat[i][j]
__global__ void k_deg(const float* __restrict__ adj, float* __restrict__ dinv){
  int i = blockIdx.x;
  int t = threadIdx.x;
  if (i >= NROW){ if (t == 0) dinv[i] = 0.f; return; }
  const float4* row = (const float4*)(adj + (size_t)i * NROW);
  float s = 0.f;
  for (int idx = t; idx < NROW/4; idx += 256){
    float4 v = row[idx];
    s += (v.x + v.y) + (v.z + v.w);
  }
  #pragma unroll
  for (int off = 32; off; off >>= 1) s += __shfl_down(s, off);
  __shared__ float red[4];
  if ((t & 63) == 0) red[t >> 6] = s;
  __syncthreads();
  if (t == 0){
    float tot = (red[0] + red[1]) + (red[2] + red[3]);
    float deg = tot - adj[(size_t)i * NROW + i] + 1.0f;   // replace diag with 1
    dinv[i] = deg > 0.f ? rsqrtf(deg) : 0.f;
  }
}

// ---------------- Kernel 2: hsT[c][i] = bf16(dinv[i] * (feat @ W)[i][c])
__global__ __launch_bounds__(256) void k_featw(const float* __restrict__ feat,
        const float* __restrict__ W, const float* __restrict__ dinv,
        unsigned short* __restrict__ hsT){
  __shared__ __align__(16) float fs[32][512];   // 64 KB
  int t = threadIdx.x;
  int i0 = blockIdx.x * 32;
  // stage 32 feat rows (row-clamped; garbage rows get dinv=0 later)
  #pragma unroll
  for (int it = 0; it < 16; ++it){
    int e = it * 1024 + t * 4;
    int r = e >> 9, cc = e & 511;
    int gr = i0 + r; if (gr > NROW - 1) gr = NROW - 1;
    *(float4*)&fs[r][cc] = *(const float4*)(feat + (size_t)gr * KF + cc);
  }
  __syncthreads();
  float acc[32];
  #pragma unroll
  for (int r = 0; r < 32; ++r) acc[r] = 0.f;
  int c = t;  // one output column per thread
  for (int k = 0; k < KF; k += 4){
    float w0 = W[(k+0)*NF + c];
    float w1 = W[(k+1)*NF + c];
    float w2 = W[(k+2)*NF + c];
    float w3 = W[(k+3)*NF + c];
    #pragma unroll
    for (int r = 0; r < 32; ++r){
      float4 f = *(const float4*)&fs[r][k];   // LDS broadcast (free)
      acc[r] = fmaf(f.x, w0, acc[r]);
      acc[r] = fmaf(f.y, w1, acc[r]);
      acc[r] = fmaf(f.z, w2, acc[r]);
      acc[r] = fmaf(f.w, w3, acc[r]);
    }
  }
  // transposed write: thread owns column c -> contiguous 64B run in hsT
  unsigned short* dst = hsT + (size_t)c * MP + i0;
  #pragma unroll
  for (int r = 0; r < 32; r += 2){
    float a0 = acc[r]   * dinv[i0 + r];       // dinv==0 for padded rows
    float a1 = acc[r+1] * dinv[i0 + r + 1];
    unsigned int u = (unsigned int)bf16rne(a0) | ((unsigned int)bf16rne(a1) << 16);
    *(unsigned int*)(dst + r) = u;
  }
}

// ---------------- Kernel 3: out += Ahat_bf16 @ hs   (K split 4-ways, atomic)
__global__ __launch_bounds__(256, 2) void k_gemm(const float* __restrict__ adj,
        const unsigned short* __restrict__ hsT, float* __restrict__ out){
  __shared__ __align__(16) unsigned short Al[64][72];    // +8 pad: 144B stride
  __shared__ __align__(16) unsigned short Bl[256][72];
  int t = threadIdx.x;
  int lane = t & 63, wid = t >> 6;
  int wr = wid >> 1, wc = wid & 1;      // 2x2 waves, wave tile 32x128
  int r0 = blockIdx.x * 64;
  int by = blockIdx.y;                  // K chunks of {40,39,39,39} tiles
  int kt0 = by * 39 + (by > 0 ? 1 : 0);
  int kt1 = (by + 1) * 39 + 1;

  f32x4 acc[2][8];
  #pragma unroll
  for (int a = 0; a < 2; ++a)
    #pragma unroll
    for (int b = 0; b < 8; ++b)
      #pragma unroll
      for (int j = 0; j < 4; ++j) acc[a][b][j] = 0.f;

  int arow = t >> 4;          // 0..15
  int acol = (t & 15) * 4;    // 0..60
  int bcol = t >> 3;          // 0..31
  int bko  = (t & 7) * 8;     // 0..56

  for (int kt = kt0; kt < kt1; ++kt){
    int k0 = kt * 64;
    // ---- stage A tile (f32 -> bf16, diagonal patched, addr-clamped tail)
    #pragma unroll
    for (int it = 0; it < 4; ++it){
      int row = it * 16 + arow;
      int gr  = r0 + row;
      int gcb = k0 + acol;
      int er = gr  < NROW     ? gr  : NROW - 1;
      int ec = gcb <= NROW - 4 ? gcb : NROW - 4;   // tail cols multiply B==0
      float4 v = *(const float4*)(adj + (size_t)er * NROW + ec);
      float f0 = v.x, f1 = v.y, f2 = v.z, f3 = v.w;
      if (gr == gcb    ) f0 = 1.f;
      if (gr == gcb + 1) f1 = 1.f;
      if (gr == gcb + 2) f2 = 1.f;
      if (gr == gcb + 3) f3 = 1.f;
      unsigned int u0 = (unsigned int)bf16rne(f0) | ((unsigned int)bf16rne(f1) << 16);
      unsigned int u1 = (unsigned int)bf16rne(f2) | ((unsigned int)bf16rne(f3) << 16);
      *(uint2*)&Al[row][acol] = make_uint2(u0, u1);
    }
    // ---- stage B tile (bf16 copy from hsT; rows k>=10000 are zero-padded)
    #pragma unroll
    for (int it = 0; it < 8; ++it){
      int cc = it * 32 + bcol;
      *(uint4*)&Bl[cc][bko] = *(const uint4*)(hsT + (size_t)cc * MP + k0 + bko);
    }
    __syncthreads();
    // ---- MFMA: 2x8 fragments of 16x16, K-step 32
    #pragma unroll
    for (int kk = 0; kk < 64; kk += 32){
      short8x a0 = *(const short8x*)&Al[wr*32      + (lane & 15)][kk + (lane >> 4) * 8];
      short8x a1 = *(const short8x*)&Al[wr*32 + 16 + (lane & 15)][kk + (lane >> 4) * 8];
      #pragma unroll
      for (int ni = 0; ni < 8; ++ni){
        short8x b = *(const short8x*)&Bl[wc*128 + ni*16 + (lane & 15)][kk + (lane >> 4) * 8];
        acc[0][ni] = __builtin_amdgcn_mfma_f32_16x16x32_bf16(a0, b, acc[0][ni], 0, 0, 0);
        acc[1][ni] = __builtin_amdgcn_mfma_f32_16x16x32_bf16(a1, b, acc[1][ni], 0, 0, 0);
      }
    }
    __syncthreads();
  }
  // ---- epilogue: atomic accumulate partial K-sums (4 commutative adds/elem)
  #pragma unroll
  for (int mi = 0; mi < 2; ++mi){
    #pragma unroll
    for (int ni = 0; ni < 8; ++ni){
      int gc = wc*128 + ni*16 + (lane & 15);
      #pragma unroll
      for (int j = 0; j < 4; ++j){
        int gr = r0 + wr*32 + mi*16 + (lane >> 4) * 4 + j;
        if (gr < NROW) atomicAdd(out + (size_t)gr * NF + gc, acc[mi][ni][j]);
      }
    }
  }
}

// ---------------- Kernel 4: out = relu(dinv_i * acc + cb + eb), in place
__global__ void k_epi(float* __restrict__ out, const float* __restrict__ dinv,
                      const float* __restrict__ cb, const float* __restrict__ eb){
  int e = (blockIdx.x * 256 + threadIdx.x) * 4;
  int i = e >> 8, c = e & 255;
  float di = dinv[i];
  float4 v = *(float4*)(out + e);
  v.x = fmaxf(fmaf(v.x, di, cb[c+0] + eb[c+0]), 0.f);
  v.y = fmaxf(fmaf(v.y, di, cb[c+1] + eb[c+1]), 0.f);
  v.z = fmaxf(fmaf(v.z, di, cb[c+2] + eb[c+2]), 0.f);
  v.w = fmaxf(fmaf(v.w, di, cb[c+3] + eb[c+3]), 0.f);
  *(float4*)(out + e) = v;
}

extern "C" void kernel_launch(void* const* d_in, const int* in_sizes, int n_in,
                              void* d_out, int out_size, void* d_ws, size_t ws_size,
                              hipStream_t stream){
  const float* feat = (const float*)d_in[0];
  const float* adj  = (const float*)d_in[1];
  const float* W    = (const float*)d_in[2];
  const float* cb   = (const float*)d_in[3];
  const float* eb   = (const float*)d_in[4];
  float* out = (float*)d_out;

  // ws layout: dinv f32[10048] @0 ; hsT bf16[256][10048] @64KB  (~5.2 MB total)
  float* dinv = (float*)d_ws;
  unsigned short* hsT = (unsigned short*)((char*)d_ws + 65536);

  hipMemsetAsync(d_out, 0, (size_t)NROW * NF * sizeof(float), stream);
  k_deg  <<<MP,            256, 0, stream>>>(adj, dinv);
  k_featw<<<MP/32,         256, 0, stream>>>(feat, W, dinv, hsT);
  k_gemm <<<dim3(NTILES,4),256, 0, stream>>>(adj, hsT, out);
  k_epi  <<<(NROW*NF)/1024,256, 0, stream>>>(out, dinv, cb, eb);
}

// Round 2
// 311.706 us; speedup vs baseline: 1.0002x; 1.0002x over previous
//
#include <hip/hip_runtime.h>

#define NROW 10000
#define NF 256
#define KF 512
#define MP 10048   // 157*64, padded row/K extent
#define NTILES 157

typedef __attribute__((ext_vector_type(8))) short short8x;
typedef __attribute__((ext_vector_type(4))) float f32x4;

__device__ __forceinline__ unsigned short bf16rne(float f){
  unsigned int u = __builtin_bit_cast(unsigned int, f);
  u += 0x7fffu + ((u >> 16) & 1u);   // round-to-nearest-even
  return (unsigned short)(u >> 16);
}

// ---------------- Kernel 0: zero d_out (rocclr fillBuffer ran at 41 GB/s!)
__global__ void k_zero(float4* __restrict__ p){
  p[blockIdx.x * 256 + threadIdx.x] = make_float4(0.f, 0.f, 0.f, 0.f);
}

// ---------------- Kernel 1: dinv[i] = rsqrt(deg_i), deg_i = sum_j Ahat[i][j]
__global__ void k_deg(const float* __restrict__ adj, float* __restrict__ dinv){
  int i = blockIdx.x;
  int t = threadIdx.x;
  if (i >= NROW){ if (t == 0) dinv[i] = 0.f; return; }
  const float4* row = (const float4*)(adj + (size_t)i * NROW);
  float s = 0.f;
  for (int idx = t; idx < NROW/4; idx += 256){
    float4 v = row[idx];
    s += (v.x + v.y) + (v.z + v.w);
  }
  #pragma unroll
  for (int off = 32; off; off >>= 1) s += __shfl_down(s, off);
  __shared__ float red[4];
  if ((t & 63) == 0) red[t >> 6] = s;
  __syncthreads();
  if (t == 0){
    float tot = (red[0] + red[1]) + (red[2] + red[3]);
    float deg = tot - adj[(size_t)i * NROW + i] + 1.0f;   // replace diag with 1
    dinv[i] = deg > 0.f ? rsqrtf(deg) : 0.f;
  }
}

// ---------------- Kernel 2: hsT[c][i] = bf16(dinv[i] * (feat @ W)[i][c])
__global__ __launch_bounds__(256) void k_featw(const float* __restrict__ feat,
        const float* __restrict__ W, const float* __restrict__ dinv,
        unsigned short* __restrict__ hsT){
  __shared__ __align__(16) float fs[32][512];   // 64 KB
  int t = threadIdx.x;
  int i0 = blockIdx.x * 32;
  // stage 32 feat rows (row-clamped; garbage rows get dinv=0 later)
  #pragma unroll
  for (int it = 0; it < 16; ++it){
    int e = it * 1024 + t * 4;
    int r = e >> 9, cc = e & 511;
    int gr = i0 + r; if (gr > NROW - 1) gr = NROW - 1;
    *(float4*)&fs[r][cc] = *(const float4*)(feat + (size_t)gr * KF + cc);
  }
  __syncthreads();
  float acc[32];
  #pragma unroll
  for (int r = 0; r < 32; ++r) acc[r] = 0.f;
  int c = t;  // one output column per thread
  for (int k = 0; k < KF; k += 4){
    float w0 = W[(k+0)*NF + c];
    float w1 = W[(k+1)*NF + c];
    float w2 = W[(k+2)*NF + c];
    float w3 = W[(k+3)*NF + c];
    #pragma unroll
    for (int r = 0; r < 32; ++r){
      float4 f = *(const float4*)&fs[r][k];   // LDS broadcast (free)
      acc[r] = fmaf(f.x, w0, acc[r]);
      acc[r] = fmaf(f.y, w1, acc[r]);
      acc[r] = fmaf(f.z, w2, acc[r]);
      acc[r] = fmaf(f.w, w3, acc[r]);
    }
  }
  // transposed write: thread owns column c -> contiguous 64B run in hsT
  unsigned short* dst = hsT + (size_t)c * MP + i0;
  #pragma unroll
  for (int r = 0; r < 32; r += 2){
    float a0 = acc[r]   * dinv[i0 + r];       // dinv==0 for padded rows
    float a1 = acc[r+1] * dinv[i0 + r + 1];
    unsigned int u = (unsigned int)bf16rne(a0) | ((unsigned int)bf16rne(a1) << 16);
    *(unsigned int*)(dst + r) = u;
  }
}

// ---------------- Kernel 3: out += Ahat_bf16 @ hs   (K split 4-ways, atomic)
__global__ __launch_bounds__(256, 2) void k_gemm(const float* __restrict__ adj,
        const unsigned short* __restrict__ hsT, float* __restrict__ out){
  __shared__ __align__(16) unsigned short Al[64][72];    // +8 pad: 144B stride
  __shared__ __align__(16) unsigned short Bl[256][72];
  int t = threadIdx.x;
  int lane = t & 63, wid = t >> 6;
  int wr = wid >> 1, wc = wid & 1;      // 2x2 waves, wave tile 32x128
  int r0 = blockIdx.x * 64;
  int by = blockIdx.y;                  // K chunks of {40,39,39,39} tiles
  int kt0 = by * 39 + (by > 0 ? 1 : 0);
  int kt1 = (by + 1) * 39 + 1;

  f32x4 acc[2][8];
  #pragma unroll
  for (int a = 0; a < 2; ++a)
    #pragma unroll
    for (int b = 0; b < 8; ++b)
      #pragma unroll
      for (int j = 0; j < 4; ++j) acc[a][b][j] = 0.f;

  int arow = t >> 4;          // 0..15
  int acol = (t & 15) * 4;    // 0..60
  int bcol = t >> 3;          // 0..31
  int bko  = (t & 7) * 8;     // 0..56

  for (int kt = kt0; kt < kt1; ++kt){
    int k0 = kt * 64;
    // ---- stage A tile (f32 -> bf16, diagonal patched, addr-clamped tail)
    #pragma unroll
    for (int it = 0; it < 4; ++it){
      int row = it * 16 + arow;
      int gr  = r0 + row;
      int gcb = k0 + acol;
      int er = gr  < NROW     ? gr  : NROW - 1;
      int ec = gcb <= NROW - 4 ? gcb : NROW - 4;   // tail cols multiply B==0
      float4 v = *(const float4*)(adj + (size_t)er * NROW + ec);
      float f0 = v.x, f1 = v.y, f2 = v.z, f3 = v.w;
      if (gr == gcb    ) f0 = 1.f;
      if (gr == gcb + 1) f1 = 1.f;
      if (gr == gcb + 2) f2 = 1.f;
      if (gr == gcb + 3) f3 = 1.f;
      unsigned int u0 = (unsigned int)bf16rne(f0) | ((unsigned int)bf16rne(f1) << 16);
      unsigned int u1 = (unsigned int)bf16rne(f2) | ((unsigned int)bf16rne(f3) << 16);
      *(uint2*)&Al[row][acol] = make_uint2(u0, u1);
    }
    // ---- stage B tile (bf16 copy from hsT; rows k>=10000 are zero-padded)
    #pragma unroll
    for (int it = 0; it < 8; ++it){
      int cc = it * 32 + bcol;
      *(uint4*)&Bl[cc][bko] = *(const uint4*)(hsT + (size_t)cc * MP + k0 + bko);
    }
    __syncthreads();
    // ---- MFMA: 2x8 fragments of 16x16, K-step 32
    #pragma unroll
    for (int kk = 0; kk < 64; kk += 32){
      short8x a0 = *(const short8x*)&Al[wr*32      + (lane & 15)][kk + (lane >> 4) * 8];
      short8x a1 = *(const short8x*)&Al[wr*32 + 16 + (lane & 15)][kk + (lane >> 4) * 8];
      #pragma unroll
      for (int ni = 0; ni < 8; ++ni){
        short8x b = *(const short8x*)&Bl[wc*128 + ni*16 + (lane & 15)][kk + (lane >> 4) * 8];
        acc[0][ni] = __builtin_amdgcn_mfma_f32_16x16x32_bf16(a0, b, acc[0][ni], 0, 0, 0);
        acc[1][ni] = __builtin_amdgcn_mfma_f32_16x16x32_bf16(a1, b, acc[1][ni], 0, 0, 0);
      }
    }
    __syncthreads();
  }
  // ---- epilogue: atomic accumulate partial K-sums (4 commutative adds/elem)
  #pragma unroll
  for (int mi = 0; mi < 2; ++mi){
    #pragma unroll
    for (int ni = 0; ni < 8; ++ni){
      int gc = wc*128 + ni*16 + (lane & 15);
      #pragma unroll
      for (int j = 0; j < 4; ++j){
        int gr = r0 + wr*32 + mi*16 + (lane >> 4) * 4 + j;
        if (gr < NROW) atomicAdd(out + (size_t)gr * NF + gc, acc[mi][ni][j]);
      }
    }
  }
}

// ---------------- Kernel 4: out = relu(dinv_i * acc + cb + eb), in place
__global__ void k_epi(float* __restrict__ out, const float* __restrict__ dinv,
                      const float* __restrict__ cb, const float* __restrict__ eb){
  int e = (blockIdx.x * 256 + threadIdx.x) * 4;
  int i = e >> 8, c = e & 255;
  float di = dinv[i];
  float4 v = *(float4*)(out + e);
  v.x = fmaxf(fmaf(v.x, di, cb[c+0] + eb[c+0]), 0.f);
  v.y = fmaxf(fmaf(v.y, di, cb[c+1] + eb[c+1]), 0.f);
  v.z = fmaxf(fmaf(v.z, di, cb[c+2] + eb[c+2]), 0.f);
  v.w = fmaxf(fmaf(v.w, di, cb[c+3] + eb[c+3]), 0.f);
  *(float4*)(out + e) = v;
}

extern "C" void kernel_launch(void* const* d_in, const int* in_sizes, int n_in,
                              void* d_out, int out_size, void* d_ws, size_t ws_size,
                              hipStream_t stream){
  const float* feat = (const float*)d_in[0];
  const float* adj  = (const float*)d_in[1];
  const float* W    = (const float*)d_in[2];
  const float* cb   = (const float*)d_in[3];
  const float* eb   = (const float*)d_in[4];
  float* out = (float*)d_out;

  // ws layout: dinv f32[10048] @0 ; hsT bf16[256][10048] @64KB  (~5.2 MB total)
  float* dinv = (float*)d_ws;
  unsigned short* hsT = (unsigned short*)((char*)d_ws + 65536);

  // custom zero-fill: rocclr fillBufferAligned measured 41 GB/s (~240 us);
  // this float4 store kernel should hit ~6 TB/s (~2 us).
  k_zero <<<(NROW*NF)/1024, 256, 0, stream>>>((float4*)out);
  k_deg  <<<MP,            256, 0, stream>>>(adj, dinv);
  k_featw<<<MP/32,         256, 0, stream>>>(feat, W, dinv, hsT);
  k_gemm <<<dim3(NTILES,4),256, 0, stream>>>(adj, hsT, out);
  k_epi  <<<(NROW*NF)/1024,256, 0, stream>>>(out, dinv, cb, eb);
}